// Round 10
// baseline (200.942 us; speedup 1.0000x reference)
//
#include <hip/hip_runtime.h>
#include <math.h>

#define DM   1024
#define DS   64
#define BATCH 8
#define SEQ  2048
#define CL   32          // chunk length
#define NC   64          // number of chunks (SEQ/CL)

typedef __bf16 bf16x8 __attribute__((ext_vector_type(8)));
typedef float  f32x4  __attribute__((ext_vector_type(4)));

#if __has_builtin(__builtin_amdgcn_exp2f)
#define EXP2(v) __builtin_amdgcn_exp2f(v)
#else
#define EXP2(v) __expf(0.69314718056f * (v))
#endif

// ---------------------------------------------------------------------------
// Kernel W: pre-convert W_delta|W_Bp|W_Cp into packed bf16, K-tiled:
// Wp[(kt*192 + n)*32 + kk], k = kt*32+kk (kt = 32-wide K slab).
// ---------------------------------------------------------------------------
__global__ __launch_bounds__(256) void wconv_kernel(
    const float* __restrict__ Wd, const float* __restrict__ Wb,
    const float* __restrict__ Wc, __bf16* __restrict__ Wp)
{
    int idx = blockIdx.x * 256 + threadIdx.x;   // n*1024 + k
    int k  = idx & 1023;
    int n  = idx >> 10;                          // 0..191
    const float* W = (n < 64) ? Wd : (n < 128 ? Wb : Wc);
    float v = W[(size_t)(n & 63) * DM + k];
    int kt = k >> 5, kk = k & 31;
    Wp[((size_t)kt * 192 + n) * 32 + kk] = (__bf16)v;
}

// ---------------------------------------------------------------------------
// Kernel A: MFMA projection v9 — 4 barrier domains per CU.
// r9 evidence: 2 blocks/CU = 2 barrier domains -> every per-iter vmcnt
// drain stalls half the CU (Occupancy 18.5%, MfmaUtil 4.6%).  v9: block =
// 128 thr (2 waves), M32 x N96, grid (512 M, 2 N-halves) = 1024 blocks ->
// 4 independent blocks/CU (LDS 28.8 KB), same 8 waves/CU but 4 independent
// barrier schedules.  BK=64, double-buffered sB (2 x 12 KB), async
// global_load_lds staging.  Pass1 de-fused (net-zero in r9, freed 16 KB).
// sB layout == Wp sublayout: chunk g (16B) covers (ktl=g>=384, n_local=
// (g-384*ktl)>>2, c4=g&3); dst = sB + g*16B (wave-uniform + lane*16).
// MFMA layouts (m89/m91): A/B frag [k=quad*8+j][m|n=l15]; D: col=l15,
// row=quad*4+reg.
// ---------------------------------------------------------------------------
__global__ __launch_bounds__(128, 2) void proj_kernel(
    const float* __restrict__ x, const __bf16* __restrict__ Wp,
    const float* __restrict__ bd, const float* __restrict__ bb,
    const float* __restrict__ bc,
    float* __restrict__ delta_g, float* __restrict__ u_g,
    float* __restrict__ ct_g)
{
    __shared__ __bf16 sB[2][6144];               // 2 x 12 KB  (2 kt-slabs x 96 x 32)
    __shared__ __bf16 sA[2][32 * 72];            // 2 x 4.5 KB

    const int tid  = threadIdx.x;                // 0..127
    const int row0 = blockIdx.x * 32;
    const int nh   = blockIdx.y;                 // 0..1: N-half (96 cols)

    const int lane = tid & 63, wv = tid >> 6;    // wv 0..1
    const int l15  = lane & 15, quad = lane >> 4;

    const int am = tid >> 2;                     // staging row 0..31
    const int ak = tid & 3;                      // 16-float k-group 0..3
    const float* xga = x + (size_t)(row0 + am) * DM + ak * 16;

    f32x4 acc[2][3];
    #pragma unroll
    for (int mt = 0; mt < 2; ++mt)
        #pragma unroll
        for (int nt = 0; nt < 3; ++nt)
            acc[mt][nt] = (f32x4){0.f, 0.f, 0.f, 0.f};

    float4 areg[4];

#if __has_builtin(__builtin_amdgcn_global_load_lds)
    #define LOADB(kb, bi) do {                                                \
        _Pragma("unroll")                                                     \
        for (int it = 0; it < 6; ++it) {                                      \
            int g   = tid + it * 128;                                         \
            int ktl = (it >= 3) ? 1 : 0;                                      \
            int r   = g - ktl * 384;                                          \
            const __bf16* gsrc = Wp +                                         \
                ((size_t)((kb) * 2 + ktl) * 192 + nh * 96 + (r >> 2)) * 32    \
                + (r & 3) * 8;                                                \
            __bf16* ldst = &sB[bi][g * 8];                                    \
            __builtin_amdgcn_global_load_lds(                                 \
                (const __attribute__((address_space(1))) void*)gsrc,          \
                (__attribute__((address_space(3))) void*)ldst, 16, 0, 0);     \
        }                                                                     \
    } while (0)
#else
    #define LOADB(kb, bi) do {                                                \
        _Pragma("unroll")                                                     \
        for (int it = 0; it < 6; ++it) {                                      \
            int g   = tid + it * 128;                                         \
            int ktl = (it >= 3) ? 1 : 0;                                      \
            int r   = g - ktl * 384;                                          \
            uint4 t = *(const uint4*)(Wp +                                    \
                ((size_t)((kb) * 2 + ktl) * 192 + nh * 96 + (r >> 2)) * 32    \
                + (r & 3) * 8);                                               \
            *(uint4*)&sB[bi][g * 8] = t;                                      \
        }                                                                     \
    } while (0)
#endif
    #define LOADA(kb) do {                                                    \
        _Pragma("unroll")                                                     \
        for (int p = 0; p < 4; ++p)                                           \
            areg[p] = *(const float4*)(xga + (kb) * 64 + p * 4);              \
    } while (0)
    #define STAGEA(bi) do {                                                   \
        bf16x8 h0 = {(__bf16)areg[0].x, (__bf16)areg[0].y,                    \
                     (__bf16)areg[0].z, (__bf16)areg[0].w,                    \
                     (__bf16)areg[1].x, (__bf16)areg[1].y,                    \
                     (__bf16)areg[1].z, (__bf16)areg[1].w};                   \
        bf16x8 h1 = {(__bf16)areg[2].x, (__bf16)areg[2].y,                    \
                     (__bf16)areg[2].z, (__bf16)areg[2].w,                    \
                     (__bf16)areg[3].x, (__bf16)areg[3].y,                    \
                     (__bf16)areg[3].z, (__bf16)areg[3].w};                   \
        *(bf16x8*)&sA[bi][am * 72 + ak * 16] = h0;                            \
        *(bf16x8*)&sA[bi][am * 72 + ak * 16 + 8] = h1;                        \
    } while (0)
    #define COMPUTE(bi) do {                                                  \
        _Pragma("unroll")                                                     \
        for (int s = 0; s < 2; ++s) {                                         \
            bf16x8 af[2];                                                     \
            _Pragma("unroll")                                                 \
            for (int mt = 0; mt < 2; ++mt)                                    \
                af[mt] = *(const bf16x8*)                                     \
                    &sA[bi][(mt * 16 + l15) * 72 + s * 32 + quad * 8];        \
            _Pragma("unroll")                                                 \
            for (int nt = 0; nt < 3; ++nt) {                                  \
                bf16x8 bv = *(const bf16x8*)                                  \
                    &sB[bi][s * 3072 + (wv * 48 + nt * 16 + l15) * 32         \
                            + quad * 8];                                      \
                _Pragma("unroll")                                             \
                for (int mt = 0; mt < 2; ++mt)                                \
                    acc[mt][nt] = __builtin_amdgcn_mfma_f32_16x16x32_bf16(    \
                        af[mt], bv, acc[mt][nt], 0, 0, 0);                    \
            }                                                                 \
        }                                                                     \
    } while (0)

    LOADB(0, 0);
    LOADA(0);
    STAGEA(0);
    __syncthreads();

    int buf = 0;
    for (int kb = 0; kb < 16; ++kb) {
        if (kb < 15) {
            LOADB(kb + 1, buf ^ 1);              // async global->LDS
            LOADA(kb + 1);
        }
        COMPUTE(buf);
        if (kb < 15) STAGEA(buf ^ 1);
        __syncthreads();                         // one barrier per iter
        buf ^= 1;
    }
    #undef LOADB
    #undef LOADA
    #undef STAGEA
    #undef COMPUTE

    // epilogue: bias + activations + stores (16-wide N windows never cross
    // a 64-wide mat boundary)
    #pragma unroll
    for (int nt = 0; nt < 3; ++nt) {
        int nwin = nh * 96 + wv * 48 + nt * 16;
        int gn   = nwin + l15;                   // 0..191
        int mat  = nwin >> 6;                    // wave-uniform per nt
        int col  = gn & 63;
        float bias = (mat == 0) ? bd[col] : (mat == 1 ? bb[col] : bc[col]);
        #pragma unroll
        for (int mt = 0; mt < 2; ++mt) {
            #pragma unroll
            for (int r = 0; r < 4; ++r) {
                int m = row0 + mt * 16 + quad * 4 + r;
                float v = acc[mt][nt][r] + bias;
                if (mat == 0) {
                    float sp = (v > 20.f) ? v : __logf(1.f + __expf(v));
                    delta_g[(size_t)m * DS + col] = sp;
                } else if (mat == 1) {
                    u_g[(size_t)m * DS + col] = v * x[(size_t)m * DM + col];
                } else {
                    ct_g[(size_t)m * DS + col] = v;
                }
            }
        }
    }
}

// ---------------------------------------------------------------------------
// Kernel B (pass 1): per-chunk local recurrence from h=0 (r6 version).
// ---------------------------------------------------------------------------
__global__ __launch_bounds__(256) void pass1_kernel(
    const float* __restrict__ delta_g, const float* __restrict__ u_g,
    const float* __restrict__ A_log,
    float* __restrict__ E, float* __restrict__ Dsum)
{
    __shared__ float s_d[CL * 64];
    __shared__ float s_u[CL * 64];
    const int c = blockIdx.x, b = blockIdx.y, tid = threadIdx.x;
    const int t0 = c * CL;

    const float4* dg = (const float4*)(delta_g + ((size_t)b * SEQ + t0) * DS);
    const float4* ug = (const float4*)(u_g     + ((size_t)b * SEQ + t0) * DS);
    #pragma unroll
    for (int it = 0; it < (CL * 64 / 4) / 256; ++it) {
        int f = tid + it * 256;
        ((float4*)s_d)[f] = dg[f];
        ((float4*)s_u)[f] = ug[f];
    }

    const int i  = tid & 63;
    const int jg = tid >> 6;
    float alog[16];
    {
        const float4* ar = (const float4*)(A_log + i * 64 + jg * 16);
        #pragma unroll
        for (int qq = 0; qq < 4; ++qq) {
            float4 v = ar[qq];
            alog[4*qq+0] = v.x * 1.44269504f; alog[4*qq+1] = v.y * 1.44269504f;
            alog[4*qq+2] = v.z * 1.44269504f; alog[4*qq+3] = v.w * 1.44269504f;
        }
    }
    __syncthreads();

    float h[16];
    #pragma unroll
    for (int k = 0; k < 16; ++k) h[k] = 0.f;
    float dsum = 0.f;

    for (int t = 0; t < CL; ++t) {
        float d = s_d[t * 64 + i];
        dsum += d;
        const float* up = s_u + t * 64 + jg * 16;
        #pragma unroll
        for (int k = 0; k < 16; ++k)
            h[k] = EXP2(alog[k] * d) * h[k] + up[k];
    }

    float* eo = E + (((size_t)c * BATCH + b) * 64 + i) * 64 + jg * 16;
    #pragma unroll
    for (int qq = 0; qq < 4; ++qq)
        ((float4*)eo)[qq] = make_float4(h[4*qq], h[4*qq+1], h[4*qq+2], h[4*qq+3]);
    if (jg == 0) Dsum[((size_t)c * BATCH + b) * 64 + i] = dsum;
}

// ---------------------------------------------------------------------------
// Kernel C (pass2ck): sequential chunk scan over all 64 chunks, parallel
// over B*64*64 elements; stores CHECKPOINT state only at chunks 8,16,..,56
// (state entering that chunk).  0.9 MB written vs 16 MB full Sin.
// ---------------------------------------------------------------------------
__global__ __launch_bounds__(256) void pass2ck_kernel(
    const float* __restrict__ A_log, const float* __restrict__ E,
    const float* __restrict__ Dsum, float* __restrict__ Sck)
{
    const int g = blockIdx.x * 256 + threadIdx.x;     // 0..32767
    const int b = g >> 12;
    const int e = g & 4095;
    const int i = e >> 6;
    const float al = A_log[e] * 1.44269504f;

    float Eb[8], db[8];
    #pragma unroll
    for (int p = 0; p < 8; ++p) {
        size_t nb = (size_t)p * BATCH + b;
        Eb[p] = E[nb * 4096 + e];
        db[p] = EXP2(al * Dsum[nb * 64 + i]);
    }

    float carry = 0.f;
    #pragma unroll 8
    for (int c = 0; c < NC; ++c) {
        const int s = c & 7;
        float Ec = Eb[s], dc = db[s];
        if (c + 8 < NC) {
            size_t nb = (size_t)(c + 8) * BATCH + b;
            Eb[s] = E[nb * 4096 + e];
            db[s] = EXP2(al * Dsum[nb * 64 + i]);
        }
        if (c > 0 && (c & 7) == 0)
            Sck[(((size_t)(c >> 3) - 1) * BATCH + b) * 4096 + e] = carry;
        carry = dc * carry + Ec;                      // the only serial dep
    }
}

// ---------------------------------------------------------------------------
// Kernel D (pass3ck): block (c,b) starts from the nearest checkpoint,
// rescans <=7 chunks (was avg 32 -> tail imbalance gone), then replays its
// chunk and emits y.  (i = tid>>2, jg = tid&3): 4 j-partials per i in
// adjacent lanes -> 2x shfl_xor, no in-loop barriers.
// ---------------------------------------------------------------------------
__global__ __launch_bounds__(256) void pass3ck_kernel(
    const float* __restrict__ delta_g, const float* __restrict__ u_g,
    const float* __restrict__ ct_g, const float* __restrict__ A_log,
    const float* __restrict__ E, const float* __restrict__ Dsum,
    const float* __restrict__ Sck, float* __restrict__ out)
{
    __shared__ float s_d[CL * 64];
    __shared__ float s_u[CL * 64];
    __shared__ float s_c[CL * 64];

    const int c = blockIdx.x, b = blockIdx.y, tid = threadIdx.x;
    const int t0 = c * CL;

    const float4* dg = (const float4*)(delta_g + ((size_t)b * SEQ + t0) * DS);
    const float4* ug = (const float4*)(u_g     + ((size_t)b * SEQ + t0) * DS);
    const float4* cg = (const float4*)(ct_g    + ((size_t)b * SEQ + t0) * DS);
    #pragma unroll
    for (int it = 0; it < (CL * 64 / 4) / 256; ++it) {
        int f = tid + it * 256;
        ((float4*)s_d)[f] = dg[f];
        ((float4*)s_u)[f] = ug[f];
        ((float4*)s_c)[f] = cg[f];
    }

    const int i  = tid >> 2;                          // 0..63
    const int jg = tid & 3;                           // 0..3
    const int e  = i * 64 + jg * 16;

    float alog[16];
    {
        const float4* ar = (const float4*)(A_log + i * 64 + jg * 16);
        #pragma unroll
        for (int qq = 0; qq < 4; ++qq) {
            float4 v = ar[qq];
            alog[4*qq+0] = v.x * 1.44269504f; alog[4*qq+1] = v.y * 1.44269504f;
            alog[4*qq+2] = v.z * 1.44269504f; alog[4*qq+3] = v.w * 1.44269504f;
        }
    }

    // ---- incoming state: checkpoint + short rescan ----
    float h[16];
    #pragma unroll
    for (int k = 0; k < 16; ++k) h[k] = 0.f;

    if (c >= 8) {
        const float4* sp = (const float4*)(
            Sck + (((size_t)(c >> 3) - 1) * BATCH + b) * 4096 + e);
        float4 s0 = sp[0], s1 = sp[1], s2 = sp[2], s3 = sp[3];
        h[0]=s0.x; h[1]=s0.y; h[2]=s0.z; h[3]=s0.w;
        h[4]=s1.x; h[5]=s1.y; h[6]=s1.z; h[7]=s1.w;
        h[8]=s2.x; h[9]=s2.y; h[10]=s2.z; h[11]=s2.w;
        h[12]=s3.x; h[13]=s3.y; h[14]=s3.z; h[15]=s3.w;
    }
    const int c0 = c & ~7;
    for (int cp = c0; cp < c; ++cp) {
        float ds = Dsum[((size_t)cp * BATCH + b) * 64 + i];
        const float4* ep = (const float4*)(
            E + ((size_t)cp * BATCH + b) * 4096 + e);
        float4 e0 = ep[0], e1 = ep[1], e2 = ep[2], e3 = ep[3];
        float ev[16] = {e0.x,e0.y,e0.z,e0.w, e1.x,e1.y,e1.z,e1.w,
                        e2.x,e2.y,e2.z,e2.w, e3.x,e3.y,e3.z,e3.w};
        #pragma unroll
        for (int k = 0; k < 16; ++k)
            h[k] = EXP2(alog[k] * ds) * h[k] + ev[k];
    }
    __syncthreads();

    // ---- replay + output ----
    for (int t = 0; t < CL; ++t) {
        float d = s_d[t * 64 + i];
        const float* up  = s_u + t * 64 + jg * 16;
        const float* cp2 = s_c + t * 64 + jg * 16;
        float part = 0.f;
        #pragma unroll
        for (int k = 0; k < 16; ++k) {
            h[k] = EXP2(alog[k] * d) * h[k] + up[k];
            part += cp2[k] * h[k];
        }
        part += __shfl_xor(part, 1);
        part += __shfl_xor(part, 2);
        if (jg == 0)
            out[((size_t)b * SEQ + t0 + t) * DS + i] = part;
    }
}

// ---------------------------------------------------------------------------
// Inputs: 0:x 1..6:(cog/beh/env dead) 7:W_delta 8:b_delta 9:W_Bp 10:b_Bp
//         11:W_Cp 12:b_Cp 13:A_log
// ---------------------------------------------------------------------------
extern "C" void kernel_launch(void* const* d_in, const int* in_sizes, int n_in,
                              void* d_out, int out_size, void* d_ws, size_t ws_size,
                              hipStream_t stream)
{
    const float* x     = (const float*)d_in[0];
    const float* Wd    = (const float*)d_in[7];
    const float* bd    = (const float*)d_in[8];
    const float* Wb    = (const float*)d_in[9];
    const float* bb    = (const float*)d_in[10];
    const float* Wc    = (const float*)d_in[11];
    const float* bc    = (const float*)d_in[12];
    const float* A_log = (const float*)d_in[13];
    float* out = (float*)d_out;

    float* ws = (float*)d_ws;
    float* delta_g = ws;                       // 1,048,576 floats
    float* u_g     = ws + 1 * 1048576;         // 1,048,576
    float* ct_g    = ws + 2 * 1048576;         // 1,048,576
    float* E       = ws + 3 * 1048576;         // 2,097,152
    float* Dsum    = ws + 5 * 1048576;         // 32,768
    float* Sck     = ws + 5 * 1048576 + 65536; // 229,376 (7 checkpoints)
    __bf16* Wp     = (__bf16*)(ws + 6 * 1048576);  // 196,608 bf16

    wconv_kernel<<<768, 256, 0, stream>>>(Wd, Wb, Wc, Wp);
    proj_kernel<<<dim3(512, 2), 128, 0, stream>>>(
        x, Wp, bd, bb, bc, delta_g, u_g, ct_g);
    pass1_kernel<<<dim3(NC, BATCH), 256, 0, stream>>>(
        delta_g, u_g, A_log, E, Dsum);
    pass2ck_kernel<<<128, 256, 0, stream>>>(
        A_log, E, Dsum, Sck);
    pass3ck_kernel<<<dim3(NC, BATCH), 256, 0, stream>>>(
        delta_g, u_g, ct_g, A_log, E, Dsum, Sck, out);
}